// Round 1
// baseline (704.469 us; speedup 1.0000x reference)
//
#include <hip/hip_runtime.h>
#include <hip/hip_bf16.h>
#include <math.h>

// Problem constants
#define B_    1024
#define D_    512
#define V_    100000
#define V_PAD 100096          // 782 * 128, also 391 * 256
#define EPS_  1e-7f
#define COSM  0.9210609940028851f   // cos(0.4)
#define SINM  0.3894183423086505f   // sin(0.4)

typedef __bf16 bf16x8 __attribute__((ext_vector_type(8)));
typedef float  f32x4  __attribute__((ext_vector_type(4)));

struct alignas(16) US8 { unsigned short h[8]; };

// round-to-nearest-even float -> bf16 bits (inputs are finite, no NaN path)
__device__ __forceinline__ unsigned short f2bf(float f) {
  union { float f; unsigned u; } a; a.f = f;
  unsigned u = a.u;
  u += 0x7FFFu + ((u >> 16) & 1u);
  return (unsigned short)(u >> 16);
}

__device__ __forceinline__ void async_copy16(void* lds, const void* g) {
  __builtin_amdgcn_global_load_lds(
      (const __attribute__((address_space(1))) void*)g,
      (__attribute__((address_space(3))) void*)lds, 16, 0, 0);
}

// ---------------------------------------------------------------------------
// Kernel 1: L2-normalize rows of x, emit bf16; zero the per-row exp-sum S.
// grid 256 x block 256 (4 waves = 4 rows per block)
// ---------------------------------------------------------------------------
__global__ void x_prep(const float* __restrict__ x,
                       unsigned short* __restrict__ xb,
                       float* __restrict__ S) {
  int t = threadIdx.x;
  int lane = t & 63, wave = t >> 6;
  int row = blockIdx.x * 4 + wave;
  const float* xr = x + (size_t)row * D_;
  f32x4 a = *(const f32x4*)(xr + lane * 8);
  f32x4 b = *(const f32x4*)(xr + lane * 8 + 4);
  float ss = a[0]*a[0] + a[1]*a[1] + a[2]*a[2] + a[3]*a[3]
           + b[0]*b[0] + b[1]*b[1] + b[2]*b[2] + b[3]*b[3];
#pragma unroll
  for (int off = 32; off > 0; off >>= 1) ss += __shfl_xor(ss, off, 64);
  float inv = 1.0f / fmaxf(sqrtf(ss), 1e-12f);
  US8 pk;
#pragma unroll
  for (int j = 0; j < 4; ++j) pk.h[j]     = f2bf(a[j] * inv);
#pragma unroll
  for (int j = 0; j < 4; ++j) pk.h[4 + j] = f2bf(b[j] * inv);
  *(US8*)(xb + (size_t)row * D_ + lane * 8) = pk;
  if (lane == 0) S[row] = 0.0f;
}

// ---------------------------------------------------------------------------
// Kernel 2: one pass over weight (D,V): per-column inv-norm + bf16 transposed
// copy wbT[v][d] (pad columns -> zeros). grid 391 x block 256; each block
// covers 256 columns, each thread 4 columns x 128 d-rows.
// ---------------------------------------------------------------------------
__global__ void w_prep(const float* __restrict__ w,
                       unsigned short* __restrict__ wbT,
                       float* __restrict__ invw) {
  __shared__ float red[4][256];
  int t = threadIdx.x;
  int vb = blockIdx.x * 256;
  int c0 = (t & 63) * 4;        // local col base (0..252)
  int dpart = t >> 6;           // 0..3 -> d range [dpart*128, +128)
  bool tvalid = (vb + c0) < V_; // V_ % 4 == 0 -> all-or-nothing per thread
  float ss0 = 0, ss1 = 0, ss2 = 0, ss3 = 0;
  US8 pk0, pk1, pk2, pk3;
  const float* wp = w + (size_t)(dpart * 128) * V_ + vb + c0;
  unsigned short* wo = wbT + (size_t)(vb + c0) * D_ + dpart * 128;
  for (int dd = 0; dd < 128; ++dd) {
    f32x4 val = {0.0f, 0.0f, 0.0f, 0.0f};
    if (tvalid) val = *(const f32x4*)(wp + (size_t)dd * V_);
    ss0 += val[0]*val[0]; ss1 += val[1]*val[1];
    ss2 += val[2]*val[2]; ss3 += val[3]*val[3];
    int sl = dd & 7;
    pk0.h[sl] = f2bf(val[0]); pk1.h[sl] = f2bf(val[1]);
    pk2.h[sl] = f2bf(val[2]); pk3.h[sl] = f2bf(val[3]);
    if (sl == 7) {
      int dbase = dd - 7;
      *(US8*)(wo + 0 * D_ + dbase) = pk0;
      *(US8*)(wo + 1 * D_ + dbase) = pk1;
      *(US8*)(wo + 2 * D_ + dbase) = pk2;
      *(US8*)(wo + 3 * D_ + dbase) = pk3;
    }
  }
  red[dpart][c0 + 0] = ss0; red[dpart][c0 + 1] = ss1;
  red[dpart][c0 + 2] = ss2; red[dpart][c0 + 3] = ss3;
  __syncthreads();
  int v = vb + t;
  float tot = red[0][t] + red[1][t] + red[2][t] + red[3][t];
  invw[v] = (v < V_) ? 1.0f / fmaxf(sqrtf(tot), 1e-12f) : 0.0f;
}

// ---------------------------------------------------------------------------
// Kernel 3: 128x128 bf16 MFMA GEMM (K=512, BK=32) with fused ArcFace epilogue:
// cosine = dot * invw, clip, margin at label col, exp, row-reduce, atomicAdd.
// grid (8 m-tiles, 782 n-tiles) x block 256 (4 waves, 2x2 of 64x64).
// ---------------------------------------------------------------------------
#define BM 128
#define BN 128
#define BK 32

__global__ __launch_bounds__(256) void gemm_epi(
    const unsigned short* __restrict__ xb,
    const unsigned short* __restrict__ wbT,
    const float* __restrict__ invw,
    const int* __restrict__ labels,
    float* __restrict__ S, float* __restrict__ Lb) {
  __shared__ unsigned short Ab[BM * BK];  // [m][k], k contiguous
  __shared__ unsigned short Bb[BN * BK];  // [n][k], k contiguous
  __shared__ int labT[BM];
  int t = threadIdx.x;
  int tm = blockIdx.x;   // 0..7
  int tn = blockIdx.y;   // 0..781
  int m0 = tm * BM, n0 = tn * BN;
  if (t < BM) labT[t] = labels[m0 + t];
  int lane = t & 63;
  int q = lane >> 4, l15 = lane & 15;
  int wave = t >> 6;
  int wm = (wave & 1) * 64, wn = (wave >> 1) * 64;
  f32x4 acc[4][4] = {};

  // staging: chunk c in [0,512): m = c>>2, k-offset = (c&3)*8; LDS elem = c*8
  int mA0 = t >> 2, kc0 = (t & 3) * 8;
  const unsigned short* gA0 = xb  + (size_t)(m0 + mA0) * D_ + kc0;
  const unsigned short* gA1 = gA0 + (size_t)64 * D_;
  const unsigned short* gB0 = wbT + (size_t)(n0 + mA0) * D_ + kc0;
  const unsigned short* gB1 = gB0 + (size_t)64 * D_;
  unsigned short* lA0 = Ab + t * 8;
  unsigned short* lA1 = Ab + (t + 256) * 8;
  unsigned short* lB0 = Bb + t * 8;
  unsigned short* lB1 = Bb + (t + 256) * 8;

  for (int kt = 0; kt < D_; kt += BK) {
    async_copy16(lA0, gA0 + kt);
    async_copy16(lA1, gA1 + kt);
    async_copy16(lB0, gB0 + kt);
    async_copy16(lB1, gB1 + kt);
    __syncthreads();
    bf16x8 af[4], bfr[4];
#pragma unroll
    for (int ri = 0; ri < 4; ++ri)
      af[ri] = *(const bf16x8*)&Ab[(wm + ri * 16 + l15) * BK + q * 8];
#pragma unroll
    for (int ci = 0; ci < 4; ++ci)
      bfr[ci] = *(const bf16x8*)&Bb[(wn + ci * 16 + l15) * BK + q * 8];
#pragma unroll
    for (int ri = 0; ri < 4; ++ri)
#pragma unroll
      for (int ci = 0; ci < 4; ++ci)
        acc[ri][ci] = __builtin_amdgcn_mfma_f32_16x16x32_bf16(
            af[ri], bfr[ci], acc[ri][ci], 0, 0, 0);
    __syncthreads();
  }

  // epilogue: C/D layout col = lane&15 (B/n side), row = q*4 + reg (A/m side)
  float iw[4]; int vcol[4];
#pragma unroll
  for (int ci = 0; ci < 4; ++ci) {
    vcol[ci] = n0 + wn + ci * 16 + l15;
    iw[ci] = invw[vcol[ci]];           // pad cols have invw = 0, in-bounds
  }
#pragma unroll
  for (int ri = 0; ri < 4; ++ri) {
#pragma unroll
    for (int reg = 0; reg < 4; ++reg) {
      int ml = wm + ri * 16 + q * 4 + reg;
      int r = m0 + ml;
      int lab = labT[ml];
      float s = 0.0f;
#pragma unroll
      for (int ci = 0; ci < 4; ++ci) {
        float c = acc[ri][ci][reg] * iw[ci];
        c = fminf(fmaxf(c, -1.0f + EPS_), 1.0f - EPS_);
        float logit = c;
        if (vcol[ci] == lab) {
          logit = c * COSM - sqrtf(fmaxf(1.0f - c * c, 0.0f)) * SINM;
          Lb[r] = logit;               // unique writer across grid
        }
        s += (vcol[ci] < V_) ? __expf(logit) : 0.0f;
      }
      // reduce across the 16 lanes of this quad (cols) -> 64-col sum
      s += __shfl_xor(s, 1, 64);
      s += __shfl_xor(s, 2, 64);
      s += __shfl_xor(s, 4, 64);
      s += __shfl_xor(s, 8, 64);
      if (l15 == 0) atomicAdd(&S[r], s);
    }
  }
}

// ---------------------------------------------------------------------------
// Kernel 4: loss = mean(log(S) - label_logit)
// ---------------------------------------------------------------------------
__global__ void finalk(const float* __restrict__ S, const float* __restrict__ Lb,
                       float* __restrict__ out) {
  __shared__ float red[256];
  int t = threadIdx.x;
  float s = 0.0f;
  for (int i = t; i < B_; i += 256) s += logf(S[i]) - Lb[i];
  red[t] = s;
  __syncthreads();
  for (int o = 128; o > 0; o >>= 1) {
    if (t < o) red[t] += red[t + o];
    __syncthreads();
  }
  if (t == 0) out[0] = red[0] * (1.0f / B_);
}

// ---------------------------------------------------------------------------
extern "C" void kernel_launch(void* const* d_in, const int* in_sizes, int n_in,
                              void* d_out, int out_size, void* d_ws, size_t ws_size,
                              hipStream_t stream) {
  const float* x = (const float*)d_in[0];
  const float* w = (const float*)d_in[1];
  const int* labels = (const int*)d_in[2];
  float* out = (float*)d_out;
  char* ws = (char*)d_ws;
  // ws layout (all 16B-aligned):
  //   wbT : V_PAD*512 bf16 = 102,498,304 B
  //   xb  : 1024*512 bf16  =   1,048,576 B
  //   invw: V_PAD f32      =     400,384 B
  //   S   : 1024 f32, Lb : 1024 f32
  unsigned short* wbT = (unsigned short*)ws;
  unsigned short* xb  = (unsigned short*)(ws + 102498304ull);
  float* invw = (float*)(ws + 103546880ull);
  float* S    = (float*)(ws + 103947264ull);
  float* Lb   = (float*)(ws + 103951360ull);

  x_prep<<<256, 256, 0, stream>>>(x, xb, S);
  w_prep<<<391, 256, 0, stream>>>(w, wbT, invw);
  gemm_epi<<<dim3(8, 782), 256, 0, stream>>>(xb, wbT, invw, labels, S, Lb);
  finalk<<<1, 256, 0, stream>>>(S, Lb, out);
}

// Round 2
// 615.844 us; speedup vs baseline: 1.1439x; 1.1439x over previous
//
#include <hip/hip_runtime.h>
#include <hip/hip_bf16.h>
#include <math.h>

// Problem constants
#define B_    1024
#define D_    512
#define V_    100000
#define V_PAD 100096          // 782 * 128, also 391 * 256
#define EPS_  1e-7f
#define COSM  0.9210609940028851f   // cos(0.4)
#define SINM  0.3894183423086505f   // sin(0.4)

typedef __bf16 bf16x8 __attribute__((ext_vector_type(8)));
typedef float  f32x4  __attribute__((ext_vector_type(4)));

struct alignas(16) US8 { unsigned short h[8]; };

// round-to-nearest-even float -> bf16 bits (inputs are finite, no NaN path)
__device__ __forceinline__ unsigned short f2bf(float f) {
  union { float f; unsigned u; } a; a.f = f;
  unsigned u = a.u;
  u += 0x7FFFu + ((u >> 16) & 1u);
  return (unsigned short)(u >> 16);
}

__device__ __forceinline__ void async_copy16(void* lds, const void* g) {
  __builtin_amdgcn_global_load_lds(
      (const __attribute__((address_space(1))) void*)g,
      (__attribute__((address_space(3))) void*)lds, 16, 0, 0);
}

// ---------------------------------------------------------------------------
// Kernel 1: L2-normalize rows of x -> bf16; zero S and the invw accumulator.
// grid 256 x block 256 (4 waves = 4 rows per block)
// ---------------------------------------------------------------------------
__global__ void x_prep(const float* __restrict__ x,
                       unsigned short* __restrict__ xb,
                       float* __restrict__ S,
                       float* __restrict__ invw) {
  int t = threadIdx.x;
  int lane = t & 63, wave = t >> 6;
  int row = blockIdx.x * 4 + wave;
  const float* xr = x + (size_t)row * D_;
  f32x4 a = *(const f32x4*)(xr + lane * 8);
  f32x4 b = *(const f32x4*)(xr + lane * 8 + 4);
  float ss = a[0]*a[0] + a[1]*a[1] + a[2]*a[2] + a[3]*a[3]
           + b[0]*b[0] + b[1]*b[1] + b[2]*b[2] + b[3]*b[3];
#pragma unroll
  for (int off = 32; off > 0; off >>= 1) ss += __shfl_xor(ss, off, 64);
  float inv = 1.0f / fmaxf(sqrtf(ss), 1e-12f);
  US8 pk;
#pragma unroll
  for (int j = 0; j < 4; ++j) pk.h[j]     = f2bf(a[j] * inv);
#pragma unroll
  for (int j = 0; j < 4; ++j) pk.h[4 + j] = f2bf(b[j] * inv);
  *(US8*)(xb + (size_t)row * D_ + lane * 8) = pk;
  if (lane == 0) S[row] = 0.0f;
  // zero the column-sum-of-squares accumulator (ws is poisoned every call)
  int i = blockIdx.x * 256 + t;
  invw[i] = 0.0f;                       // i < 65536 < V_PAD
  if (i + 65536 < V_PAD) invw[i + 65536] = 0.0f;
}

// ---------------------------------------------------------------------------
// Kernel 2: bf16 transposed cast of weight + partial column sum-of-squares.
// grid (391, 8): block = 256 cols x 64 d-rows.  3128 blocks -> latency-hiding.
// ---------------------------------------------------------------------------
__global__ void w_cast(const float* __restrict__ w,
                       unsigned short* __restrict__ wbT,
                       float* __restrict__ invw) {
  __shared__ float red[4][256];
  int t = threadIdx.x;
  int vb = blockIdx.x * 256;
  int dbase = blockIdx.y * 64;
  int c0 = (t & 63) * 4;        // local col base (0..252)
  int dpart = t >> 6;           // 0..3 -> 16 d-rows each
  bool tvalid = (vb + c0) < V_; // V_ % 4 == 0 -> all-or-nothing per thread
  float ss0 = 0, ss1 = 0, ss2 = 0, ss3 = 0;
  US8 pk0, pk1, pk2, pk3;
  const float* wp = w + (size_t)(dbase + dpart * 16) * V_ + vb + c0;
  unsigned short* wo = wbT + (size_t)(vb + c0) * D_ + dbase + dpart * 16;
  for (int dd = 0; dd < 16; ++dd) {
    f32x4 val = {0.0f, 0.0f, 0.0f, 0.0f};
    if (tvalid) val = *(const f32x4*)(wp + (size_t)dd * V_);
    ss0 += val[0]*val[0]; ss1 += val[1]*val[1];
    ss2 += val[2]*val[2]; ss3 += val[3]*val[3];
    int sl = dd & 7;
    pk0.h[sl] = f2bf(val[0]); pk1.h[sl] = f2bf(val[1]);
    pk2.h[sl] = f2bf(val[2]); pk3.h[sl] = f2bf(val[3]);
    if (sl == 7) {
      int db = dd - 7;
      *(US8*)(wo + 0 * D_ + db) = pk0;
      *(US8*)(wo + 1 * D_ + db) = pk1;
      *(US8*)(wo + 2 * D_ + db) = pk2;
      *(US8*)(wo + 3 * D_ + db) = pk3;
    }
  }
  red[dpart][c0 + 0] = ss0; red[dpart][c0 + 1] = ss1;
  red[dpart][c0 + 2] = ss2; red[dpart][c0 + 3] = ss3;
  __syncthreads();
  float tot = red[0][t] + red[1][t] + red[2][t] + red[3][t];
  atomicAdd(&invw[vb + t], tot);
}

// ---------------------------------------------------------------------------
// Kernel 2b: finalize invw = 1/max(sqrt(sumsq),1e-12); pad cols -> 0.
// ---------------------------------------------------------------------------
__global__ void w_fin(float* __restrict__ invw) {
  int v = blockIdx.x * 256 + threadIdx.x;   // < V_PAD
  float s = invw[v];
  invw[v] = (v < V_) ? 1.0f / fmaxf(sqrtf(s), 1e-12f) : 0.0f;
}

// ---------------------------------------------------------------------------
// Kernel 3: 128x128 bf16 MFMA GEMM, BK=64, XOR-swizzled LDS chunk mapping
// (conflict-free fragment reads despite global_load_lds's forced-contiguous
// LDS addressing).  Fused ArcFace epilogue.
// grid (8 m-tiles, 782 n-tiles) x block 256 (4 waves, 2x2 of 64x64).
// ---------------------------------------------------------------------------
#define BM 128
#define BN 128
#define BK 64

__global__ __launch_bounds__(256) void gemm_epi(
    const unsigned short* __restrict__ xb,
    const unsigned short* __restrict__ wbT,
    const float* __restrict__ invw,
    const int* __restrict__ labels,
    float* __restrict__ S, float* __restrict__ Lb) {
  // LDS slot p (16B chunks) holds data (m = p>>3, kc = (p&7) ^ (m&7)).
  __shared__ unsigned short Ab[BM * BK];  // 16 KB
  __shared__ unsigned short Bb[BN * BK];  // 16 KB
  __shared__ int labT[BM];
  int t = threadIdx.x;
  int tm = blockIdx.x;   // 0..7
  int tn = blockIdx.y;   // 0..781
  int m0 = tm * BM, n0 = tn * BN;
  if (t < BM) labT[t] = labels[m0 + t];
  int lane = t & 63;
  int q = lane >> 4, l15 = lane & 15;
  int wave = t >> 6;
  int wm = (wave & 1) * 64, wn = (wave >> 1) * 64;
  f32x4 acc[4][4] = {};

  // staging pointers: thread handles chunks p = t + 256*j, j=0..3 (A and B)
  const unsigned short* gA[4];
  const unsigned short* gB[4];
#pragma unroll
  for (int j = 0; j < 4; ++j) {
    int p = t + 256 * j;
    int m = p >> 3;
    int kc = (p & 7) ^ (m & 7);
    gA[j] = xb  + (size_t)(m0 + m) * D_ + kc * 8;
    gB[j] = wbT + (size_t)(n0 + m) * D_ + kc * 8;
  }

  for (int kt = 0; kt < D_; kt += BK) {
#pragma unroll
    for (int j = 0; j < 4; ++j) {
      async_copy16(Ab + (t + 256 * j) * 8, gA[j] + kt);
      async_copy16(Bb + (t + 256 * j) * 8, gB[j] + kt);
    }
    __syncthreads();
    int h = l15 & 7;
#pragma unroll
    for (int s = 0; s < 2; ++s) {
      int kx = s * 4 + q;
      bf16x8 af[4], bfr[4];
#pragma unroll
      for (int ri = 0; ri < 4; ++ri) {
        int row = wm + ri * 16 + l15;
        af[ri] = *(const bf16x8*)&Ab[(row * 8 + (kx ^ h)) * 8];
      }
#pragma unroll
      for (int ci = 0; ci < 4; ++ci) {
        int row = wn + ci * 16 + l15;
        bfr[ci] = *(const bf16x8*)&Bb[(row * 8 + (kx ^ h)) * 8];
      }
#pragma unroll
      for (int ri = 0; ri < 4; ++ri)
#pragma unroll
        for (int ci = 0; ci < 4; ++ci)
          acc[ri][ci] = __builtin_amdgcn_mfma_f32_16x16x32_bf16(
              af[ri], bfr[ci], acc[ri][ci], 0, 0, 0);
    }
    __syncthreads();
  }

  // epilogue: C/D layout col = lane&15 (n side), row = q*4 + reg (m side)
  float iw[4]; int vcol[4];
#pragma unroll
  for (int ci = 0; ci < 4; ++ci) {
    vcol[ci] = n0 + wn + ci * 16 + l15;
    iw[ci] = invw[vcol[ci]];           // pad cols have invw = 0, in-bounds
  }
#pragma unroll
  for (int ri = 0; ri < 4; ++ri) {
#pragma unroll
    for (int reg = 0; reg < 4; ++reg) {
      int ml = wm + ri * 16 + q * 4 + reg;
      int r = m0 + ml;
      int lab = labT[ml];
      float s = 0.0f;
#pragma unroll
      for (int ci = 0; ci < 4; ++ci) {
        float c = acc[ri][ci][reg] * iw[ci];
        c = fminf(fmaxf(c, -1.0f + EPS_), 1.0f - EPS_);
        float logit = c;
        if (vcol[ci] == lab) {
          logit = c * COSM - sqrtf(fmaxf(1.0f - c * c, 0.0f)) * SINM;
          Lb[r] = logit;               // unique writer across grid
        }
        s += (vcol[ci] < V_) ? __expf(logit) : 0.0f;
      }
      s += __shfl_xor(s, 1, 64);
      s += __shfl_xor(s, 2, 64);
      s += __shfl_xor(s, 4, 64);
      s += __shfl_xor(s, 8, 64);
      if (l15 == 0) atomicAdd(&S[r], s);
    }
  }
}

// ---------------------------------------------------------------------------
// Kernel 4: loss = mean(log(S) - label_logit)
// ---------------------------------------------------------------------------
__global__ void finalk(const float* __restrict__ S, const float* __restrict__ Lb,
                       float* __restrict__ out) {
  __shared__ float red[256];
  int t = threadIdx.x;
  float s = 0.0f;
  for (int i = t; i < B_; i += 256) s += logf(S[i]) - Lb[i];
  red[t] = s;
  __syncthreads();
  for (int o = 128; o > 0; o >>= 1) {
    if (t < o) red[t] += red[t + o];
    __syncthreads();
  }
  if (t == 0) out[0] = red[0] * (1.0f / B_);
}

// ---------------------------------------------------------------------------
extern "C" void kernel_launch(void* const* d_in, const int* in_sizes, int n_in,
                              void* d_out, int out_size, void* d_ws, size_t ws_size,
                              hipStream_t stream) {
  const float* x = (const float*)d_in[0];
  const float* w = (const float*)d_in[1];
  const int* labels = (const int*)d_in[2];
  float* out = (float*)d_out;
  char* ws = (char*)d_ws;
  // ws layout (all 16B-aligned):
  //   wbT : V_PAD*512 bf16 = 102,498,304 B
  //   xb  : 1024*512 bf16  =   1,048,576 B
  //   invw: V_PAD f32      =     400,384 B
  //   S   : 1024 f32, Lb : 1024 f32
  unsigned short* wbT = (unsigned short*)ws;
  unsigned short* xb  = (unsigned short*)(ws + 102498304ull);
  float* invw = (float*)(ws + 103546880ull);
  float* S    = (float*)(ws + 103947264ull);
  float* Lb   = (float*)(ws + 103951360ull);

  x_prep<<<256, 256, 0, stream>>>(x, xb, S, invw);
  w_cast<<<dim3(391, 8), 256, 0, stream>>>(w, wbT, invw);
  w_fin<<<391, 256, 0, stream>>>(invw);
  gemm_epi<<<dim3(8, 782), 256, 0, stream>>>(xb, wbT, invw, labels, S, Lb);
  finalk<<<1, 256, 0, stream>>>(S, Lb, out);
}

// Round 3
// 539.850 us; speedup vs baseline: 1.3049x; 1.1408x over previous
//
#include <hip/hip_runtime.h>
#include <hip/hip_bf16.h>
#include <math.h>

// Problem constants
#define B_    1024
#define D_    512
#define V_    100000
#define V_PAD 100096          // 782 * 128 = 1564 * 64
#define NT_   782             // n-tiles of 128
#define EPS_  1e-7f
#define COSM  0.9210609940028851f   // cos(0.4)
#define SINM  0.3894183423086505f   // sin(0.4)

typedef __bf16 bf16x8 __attribute__((ext_vector_type(8)));
typedef float  f32x4  __attribute__((ext_vector_type(4)));

struct alignas(16) US8 { unsigned short h[8]; };

// round-to-nearest-even float -> bf16 bits (inputs finite)
__device__ __forceinline__ unsigned short f2bf(float f) {
  union { float f; unsigned u; } a; a.f = f;
  unsigned u = a.u;
  u += 0x7FFFu + ((u >> 16) & 1u);
  return (unsigned short)(u >> 16);
}

__device__ __forceinline__ void async_copy16(void* lds, const void* g) {
  __builtin_amdgcn_global_load_lds(
      (const __attribute__((address_space(1))) void*)g,
      (__attribute__((address_space(3))) void*)lds, 16, 0, 0);
}

// ---------------------------------------------------------------------------
// Kernel 1: L2-normalize rows of x -> bf16; zero S.
// grid 256 x block 256 (4 waves = 4 rows per block)
// ---------------------------------------------------------------------------
__global__ void x_prep(const float* __restrict__ x,
                       unsigned short* __restrict__ xb,
                       float* __restrict__ S) {
  int t = threadIdx.x;
  int lane = t & 63, wave = t >> 6;
  int row = blockIdx.x * 4 + wave;
  const float* xr = x + (size_t)row * D_;
  f32x4 a = *(const f32x4*)(xr + lane * 8);
  f32x4 b = *(const f32x4*)(xr + lane * 8 + 4);
  float ss = a[0]*a[0] + a[1]*a[1] + a[2]*a[2] + a[3]*a[3]
           + b[0]*b[0] + b[1]*b[1] + b[2]*b[2] + b[3]*b[3];
#pragma unroll
  for (int off = 32; off > 0; off >>= 1) ss += __shfl_xor(ss, off, 64);
  float inv = 1.0f / fmaxf(sqrtf(ss), 1e-12f);
  US8 pk;
#pragma unroll
  for (int j = 0; j < 4; ++j) pk.h[j]     = f2bf(a[j] * inv);
#pragma unroll
  for (int j = 0; j < 4; ++j) pk.h[4 + j] = f2bf(b[j] * inv);
  *(US8*)(xb + (size_t)row * D_ + lane * 8) = pk;
  if (lane == 0) S[row] = 0.0f;
}

// ---------------------------------------------------------------------------
// Kernel 2: weight -> bf16 transposed copy + column inv-norms, via LDS
// transpose so BOTH global reads and global writes are fully coalesced.
// Block = 64 full columns (D=512). grid 1564. No atomics.
// Read: lane owns 1 column (64 x 4B = 256B coalesced per row), 8 rows/iter,
//   packs US8 -> chunk-XOR-swizzled ds_write_b128 (even bank spread).
// Write: wave writes one whole column: 64 lanes x 16B = 1024B contiguous.
// ---------------------------------------------------------------------------
__global__ __launch_bounds__(256) void w_cast2(const float* __restrict__ w,
                                               unsigned short* __restrict__ wbT,
                                               float* __restrict__ invw) {
  __shared__ unsigned short tile[64 * 512];   // 64 KB, chunk-swizzled
  __shared__ float red[4][64];
  int t = threadIdx.x;
  int c = t & 63;               // column owned in read phase
  int wv = t >> 6;              // wave id: owns d-slabs [wv*8 + 32k, +8)
  int vb = blockIdx.x * 64;
  bool valid = (vb + c) < V_;
  const float* wp = w + vb + c;
  float ss = 0.0f;
#pragma unroll
  for (int k = 0; k < 16; ++k) {
    int d0 = k * 32 + wv * 8;
    float v[8];
#pragma unroll
    for (int i = 0; i < 8; ++i)
      v[i] = valid ? wp[(size_t)(d0 + i) * V_] : 0.0f;
    US8 pk;
#pragma unroll
    for (int i = 0; i < 8; ++i) { ss += v[i] * v[i]; pk.h[i] = f2bf(v[i]); }
    int chunk = ((d0 >> 3) ^ c) & 63;         // swizzle: even bank spread
    *(US8*)&tile[c * 512 + chunk * 8] = pk;
  }
  red[wv][c] = ss;
  __syncthreads();
  if (t < 64) {
    float tot = red[0][t] + red[1][t] + red[2][t] + red[3][t];
    invw[vb + t] = ((vb + t) < V_) ? 1.0f / fmaxf(sqrtf(tot), 1e-12f) : 0.0f;
  }
  // write phase: wave wv writes columns [wv*16, wv*16+16)
#pragma unroll
  for (int i = 0; i < 16; ++i) {
    int cc = wv * 16 + i;
    US8 val = *(const US8*)&tile[cc * 512 + ((c ^ cc) & 63) * 8];
    *(US8*)(wbT + (size_t)(vb + cc) * D_ + c * 8) = val;
  }
}

// ---------------------------------------------------------------------------
// Kernel 3: 128x128 bf16 MFMA GEMM, BK=64, XOR-swizzled LDS (0 conflicts),
// XCD-aware block mapping: xcd = bid&7 owns a contiguous n-stripe, with the
// 8 m-tiles of one n-tile consecutive on the SAME XCD -> each B-tile fills
// one L2 once and is reused 8x. Fused ArcFace epilogue.
// grid 6272 x block 256 (4 waves, 2x2 of 64x64).
// ---------------------------------------------------------------------------
#define BM 128
#define BN 128
#define BK 64

__global__ __launch_bounds__(256) void gemm_epi(
    const unsigned short* __restrict__ xb,
    const unsigned short* __restrict__ wbT,
    const float* __restrict__ invw,
    const int* __restrict__ labels,
    float* __restrict__ S, float* __restrict__ Lb) {
  // XCD-aware swizzle (round-robin dispatch heuristic: xcd = bid % 8)
  int bid = blockIdx.x;
  int xcd = bid & 7;
  int slot = bid >> 3;          // 0..783
  int tn = xcd * 98 + (slot >> 3);
  int tm = slot & 7;
  if (tn >= NT_) return;
  int m0 = tm * BM, n0 = tn * BN;

  __shared__ unsigned short Ab[BM * BK];  // 16 KB
  __shared__ unsigned short Bb[BN * BK];  // 16 KB
  __shared__ int labT[BM];
  int t = threadIdx.x;
  if (t < BM) labT[t] = labels[m0 + t];
  int lane = t & 63;
  int q = lane >> 4, l15 = lane & 15;
  int wave = t >> 6;
  int wm = (wave & 1) * 64, wn = (wave >> 1) * 64;
  f32x4 acc[4][4] = {};

  // staging: LDS slot p (16B chunks) holds (m = p>>3, kc = (p&7) ^ (m&7))
  const unsigned short* gA[4];
  const unsigned short* gB[4];
#pragma unroll
  for (int j = 0; j < 4; ++j) {
    int p = t + 256 * j;
    int m = p >> 3;
    int kc = (p & 7) ^ (m & 7);
    gA[j] = xb  + (size_t)(m0 + m) * D_ + kc * 8;
    gB[j] = wbT + (size_t)(n0 + m) * D_ + kc * 8;
  }

  for (int kt = 0; kt < D_; kt += BK) {
#pragma unroll
    for (int j = 0; j < 4; ++j) {
      async_copy16(Ab + (t + 256 * j) * 8, gA[j] + kt);
      async_copy16(Bb + (t + 256 * j) * 8, gB[j] + kt);
    }
    __syncthreads();
    int h = l15 & 7;
#pragma unroll
    for (int s = 0; s < 2; ++s) {
      int kx = s * 4 + q;
      bf16x8 af[4], bfr[4];
#pragma unroll
      for (int ri = 0; ri < 4; ++ri) {
        int row = wm + ri * 16 + l15;
        af[ri] = *(const bf16x8*)&Ab[(row * 8 + (kx ^ h)) * 8];
      }
#pragma unroll
      for (int ci = 0; ci < 4; ++ci) {
        int row = wn + ci * 16 + l15;
        bfr[ci] = *(const bf16x8*)&Bb[(row * 8 + (kx ^ h)) * 8];
      }
#pragma unroll
      for (int ri = 0; ri < 4; ++ri)
#pragma unroll
        for (int ci = 0; ci < 4; ++ci)
          acc[ri][ci] = __builtin_amdgcn_mfma_f32_16x16x32_bf16(
              af[ri], bfr[ci], acc[ri][ci], 0, 0, 0);
    }
    __syncthreads();
  }

  // epilogue: C/D layout col = lane&15 (n side), row = q*4 + reg (m side)
  float iw[4]; int vcol[4];
#pragma unroll
  for (int ci = 0; ci < 4; ++ci) {
    vcol[ci] = n0 + wn + ci * 16 + l15;
    iw[ci] = invw[vcol[ci]];           // pad cols have invw = 0, in-bounds
  }
#pragma unroll
  for (int ri = 0; ri < 4; ++ri) {
#pragma unroll
    for (int reg = 0; reg < 4; ++reg) {
      int ml = wm + ri * 16 + q * 4 + reg;
      int r = m0 + ml;
      int lab = labT[ml];
      float s = 0.0f;
#pragma unroll
      for (int ci = 0; ci < 4; ++ci) {
        float cv = acc[ri][ci][reg] * iw[ci];
        cv = fminf(fmaxf(cv, -1.0f + EPS_), 1.0f - EPS_);
        float logit = cv;
        if (vcol[ci] == lab) {
          logit = cv * COSM - sqrtf(fmaxf(1.0f - cv * cv, 0.0f)) * SINM;
          Lb[r] = logit;               // unique writer across grid
        }
        s += (vcol[ci] < V_) ? __expf(logit) : 0.0f;
      }
      s += __shfl_xor(s, 1, 64);
      s += __shfl_xor(s, 2, 64);
      s += __shfl_xor(s, 4, 64);
      s += __shfl_xor(s, 8, 64);
      if (l15 == 0) atomicAdd(&S[r], s);
    }
  }
}

// ---------------------------------------------------------------------------
// Kernel 4: loss = mean(log(S) - label_logit)
// ---------------------------------------------------------------------------
__global__ void finalk(const float* __restrict__ S, const float* __restrict__ Lb,
                       float* __restrict__ out) {
  __shared__ float red[256];
  int t = threadIdx.x;
  float s = 0.0f;
  for (int i = t; i < B_; i += 256) s += logf(S[i]) - Lb[i];
  red[t] = s;
  __syncthreads();
  for (int o = 128; o > 0; o >>= 1) {
    if (t < o) red[t] += red[t + o];
    __syncthreads();
  }
  if (t == 0) out[0] = red[0] * (1.0f / B_);
}

// ---------------------------------------------------------------------------
extern "C" void kernel_launch(void* const* d_in, const int* in_sizes, int n_in,
                              void* d_out, int out_size, void* d_ws, size_t ws_size,
                              hipStream_t stream) {
  const float* x = (const float*)d_in[0];
  const float* w = (const float*)d_in[1];
  const int* labels = (const int*)d_in[2];
  float* out = (float*)d_out;
  char* ws = (char*)d_ws;
  // ws layout (16B-aligned):
  //   wbT : V_PAD*512 bf16 = 102,498,304 B
  //   xb  : 1024*512 bf16  =   1,048,576 B
  //   invw: V_PAD f32      =     400,384 B
  //   S   : 1024 f32, Lb : 1024 f32
  unsigned short* wbT = (unsigned short*)ws;
  unsigned short* xb  = (unsigned short*)(ws + 102498304ull);
  float* invw = (float*)(ws + 103546880ull);
  float* S    = (float*)(ws + 103947264ull);
  float* Lb   = (float*)(ws + 103951360ull);

  x_prep<<<256, 256, 0, stream>>>(x, xb, S);
  w_cast2<<<1564, 256, 0, stream>>>(w, wbT, invw);
  gemm_epi<<<6272, 256, 0, stream>>>(xb, wbT, invw, labels, S, Lb);
  finalk<<<1, 256, 0, stream>>>(S, Lb, out);
}

// Round 5
// 517.294 us; speedup vs baseline: 1.3618x; 1.0436x over previous
//
#include <hip/hip_runtime.h>
#include <hip/hip_bf16.h>
#include <math.h>

// Problem constants
#define B_    1024
#define D_    512
#define V_    100000
#define NT_   782             // n-tiles of 128 (782*128 = 100096)
#define EPS_  1e-7f
#define COSM  0.9210609940028851f   // cos(0.4)
#define SINM  0.3894183423086505f   // sin(0.4)

typedef __bf16 bf16x8 __attribute__((ext_vector_type(8)));
typedef float  f32x4  __attribute__((ext_vector_type(4)));

struct alignas(16) US8 { unsigned short h[8]; };

// round-to-nearest-even float -> bf16 bits (inputs finite)
__device__ __forceinline__ unsigned short f2bf(float f) {
  union { float f; unsigned u; } a; a.f = f;
  unsigned u = a.u;
  u += 0x7FFFu + ((u >> 16) & 1u);
  return (unsigned short)(u >> 16);
}

__device__ __forceinline__ void async_copy16(void* lds, const void* g) {
  __builtin_amdgcn_global_load_lds(
      (const __attribute__((address_space(1))) void*)g,
      (__attribute__((address_space(3))) void*)lds, 16, 0, 0);
}

// ---------------------------------------------------------------------------
// Kernel 1: L2-normalize rows of x -> bf16; zero S.
// grid 256 x block 256 (4 waves = 4 rows per block)
// ---------------------------------------------------------------------------
__global__ void x_prep(const float* __restrict__ x,
                       unsigned short* __restrict__ xb,
                       float* __restrict__ S) {
  int t = threadIdx.x;
  int lane = t & 63, wave = t >> 6;
  int row = blockIdx.x * 4 + wave;
  const float* xr = x + (size_t)row * D_;
  f32x4 a = *(const f32x4*)(xr + lane * 8);
  f32x4 b = *(const f32x4*)(xr + lane * 8 + 4);
  float ss = a[0]*a[0] + a[1]*a[1] + a[2]*a[2] + a[3]*a[3]
           + b[0]*b[0] + b[1]*b[1] + b[2]*b[2] + b[3]*b[3];
#pragma unroll
  for (int off = 32; off > 0; off >>= 1) ss += __shfl_xor(ss, off, 64);
  float inv = 1.0f / fmaxf(sqrtf(ss), 1e-12f);
  US8 pk;
#pragma unroll
  for (int j = 0; j < 4; ++j) pk.h[j]     = f2bf(a[j] * inv);
#pragma unroll
  for (int j = 0; j < 4; ++j) pk.h[4 + j] = f2bf(b[j] * inv);
  *(US8*)(xb + (size_t)row * D_ + lane * 8) = pk;
  if (lane == 0) S[row] = 0.0f;
}

// ---------------------------------------------------------------------------
// Kernel 2 (fused): 128x128 bf16 MFMA GEMM reading B straight from fp32 w.
// Per K-iter each thread loads a 4-col x 8-row fp32 sub-block (8 x dwordx4,
// 1 KB/wave-instr coalescing), casts + register-transposes to 4 US8 chunks,
// ds_write_b128 into the XOR-swizzled LDS layout (chunk index = rp).
// Column sum-of-squares accumulated per-thread, LDS-reduced -> iwL.
// A-tile via async DMA from xb (proven path).  XCD-aware block mapping.
// Fused ArcFace epilogue.  grid 6272 x block 256 (4 waves, 2x2 of 64x64).
// ---------------------------------------------------------------------------
#define BM 128
#define BN 128
#define BK 64

__global__ __launch_bounds__(256) void gemm_fused(
    const unsigned short* __restrict__ xb,
    const float* __restrict__ w,
    const int* __restrict__ labels,
    float* __restrict__ S, float* __restrict__ Lb) {
  int bid = blockIdx.x;
  int xcd = bid & 7;
  int slot = bid >> 3;          // 0..783
  int tn = xcd * 98 + (slot >> 3);
  int tm = slot & 7;
  if (tn >= NT_) return;
  int m0 = tm * BM, n0 = tn * BN;

  // LDS slot p (16B chunks) holds (m = p>>3, kc = (p&7) ^ (m&7))
  __shared__ unsigned short Ab[BM * BK];  // 16 KB
  __shared__ unsigned short Bb[BN * BK];  // 16 KB
  __shared__ float sqred[8][BN];          // 4 KB
  __shared__ float iwL[BN];
  __shared__ int labT[BM];
  int t = threadIdx.x;
  if (t < BM) labT[t] = labels[m0 + t];
  int lane = t & 63;
  int q = lane >> 4, l15 = lane & 15;
  int wave = t >> 6;
  int wm = (wave & 1) * 64, wn = (wave >> 1) * 64;
  f32x4 acc[4][4] = {};

  // ---- A staging (async DMA, proven in R2/R3) ----
  const unsigned short* gA[4];
  unsigned short* lA[4];
#pragma unroll
  for (int j = 0; j < 4; ++j) {
    int p = t + 256 * j;
    int m = p >> 3;
    int kc = (p & 7) ^ (m & 7);
    gA[j] = xb + (size_t)(m0 + m) * D_ + kc * 8;
    lA[j] = Ab + p * 8;
  }

  // ---- B staging: thread owns cols [c0l, c0l+4) x rows [rp*8, rp*8+8) ----
  int cg = t & 31;              // column group
  int rp = t >> 5;              // 0..7 -> chunk index within BK tile
  int c0l = cg * 4;
  bool vok = (n0 + c0l + 3) < V_;   // all-or-nothing (V_ % 4 == 0)
  const float* wbase = w + (size_t)rp * 8 * V_ + n0 + c0l;
  unsigned short* bdst[4];
#pragma unroll
  for (int cc = 0; cc < 4; ++cc) {
    int col = c0l + cc;
    bdst[cc] = &Bb[(col * 8 + (rp ^ (col & 7))) * 8];
  }
  float ssq[4] = {0.0f, 0.0f, 0.0f, 0.0f};

  for (int kt = 0; kt < D_; kt += BK) {
#pragma unroll
    for (int j = 0; j < 4; ++j) async_copy16(lA[j], gA[j] + kt);

    f32x4 row[8];
    if (vok) {
#pragma unroll
      for (int i = 0; i < 8; ++i)
        row[i] = *(const f32x4*)(wbase + (size_t)i * V_);
    } else {
#pragma unroll
      for (int i = 0; i < 8; ++i) row[i] = f32x4{0.0f, 0.0f, 0.0f, 0.0f};
    }
#pragma unroll
    for (int cc = 0; cc < 4; ++cc) {
      US8 pk;
#pragma unroll
      for (int i = 0; i < 8; ++i) {
        float v = row[i][cc];
        ssq[cc] += v * v;
        pk.h[i] = f2bf(v);
      }
      *(US8*)bdst[cc] = pk;
    }
    wbase += (size_t)BK * V_;

    __syncthreads();
    int h = l15 & 7;
#pragma unroll
    for (int s = 0; s < 2; ++s) {
      int kx = s * 4 + q;
      bf16x8 af[4], bfr[4];
#pragma unroll
      for (int ri = 0; ri < 4; ++ri) {
        int row_ = wm + ri * 16 + l15;
        af[ri] = *(const bf16x8*)&Ab[(row_ * 8 + (kx ^ h)) * 8];
      }
#pragma unroll
      for (int ci = 0; ci < 4; ++ci) {
        int row_ = wn + ci * 16 + l15;
        bfr[ci] = *(const bf16x8*)&Bb[(row_ * 8 + (kx ^ h)) * 8];
      }
#pragma unroll
      for (int ri = 0; ri < 4; ++ri)
#pragma unroll
        for (int ci = 0; ci < 4; ++ci)
          acc[ri][ci] = __builtin_amdgcn_mfma_f32_16x16x32_bf16(
              af[ri], bfr[ci], acc[ri][ci], 0, 0, 0);
    }
    __syncthreads();
  }

  // ---- column inv-norms: LDS reduce over the 8 row-parts ----
#pragma unroll
  for (int cc = 0; cc < 4; ++cc) sqred[rp][c0l + cc] = ssq[cc];
  __syncthreads();
  if (t < BN) {
    float tot = 0.0f;
#pragma unroll
    for (int p = 0; p < 8; ++p) tot += sqred[p][t];
    iwL[t] = ((n0 + t) < V_) ? 1.0f / fmaxf(sqrtf(tot), 1e-12f) : 0.0f;
  }
  __syncthreads();

  // ---- epilogue: C/D layout col = lane&15 (n side), row = q*4 + reg ----
  float iw[4]; int vcol[4];
#pragma unroll
  for (int ci = 0; ci < 4; ++ci) {
    int nl = wn + ci * 16 + l15;
    vcol[ci] = n0 + nl;
    iw[ci] = iwL[nl];
  }
#pragma unroll
  for (int ri = 0; ri < 4; ++ri) {
#pragma unroll
    for (int reg = 0; reg < 4; ++reg) {
      int ml = wm + ri * 16 + q * 4 + reg;
      int r = m0 + ml;
      int lab = labT[ml];
      float s = 0.0f;
#pragma unroll
      for (int ci = 0; ci < 4; ++ci) {
        float cv = acc[ri][ci][reg] * iw[ci];
        cv = fminf(fmaxf(cv, -1.0f + EPS_), 1.0f - EPS_);
        float logit = cv;
        if (vcol[ci] == lab) {
          logit = cv * COSM - sqrtf(fmaxf(1.0f - cv * cv, 0.0f)) * SINM;
          Lb[r] = logit;               // unique writer across grid
        }
        s += (vcol[ci] < V_) ? __expf(logit) : 0.0f;
      }
      s += __shfl_xor(s, 1, 64);
      s += __shfl_xor(s, 2, 64);
      s += __shfl_xor(s, 4, 64);
      s += __shfl_xor(s, 8, 64);
      if (l15 == 0) atomicAdd(&S[r], s);
    }
  }
}

// ---------------------------------------------------------------------------
// Kernel 3: loss = mean(log(S) - label_logit)
// ---------------------------------------------------------------------------
__global__ void finalk(const float* __restrict__ S, const float* __restrict__ Lb,
                       float* __restrict__ out) {
  __shared__ float red[256];
  int t = threadIdx.x;
  float s = 0.0f;
  for (int i = t; i < B_; i += 256) s += logf(S[i]) - Lb[i];
  red[t] = s;
  __syncthreads();
  for (int o = 128; o > 0; o >>= 1) {
    if (t < o) red[t] += red[t + o];
    __syncthreads();
  }
  if (t == 0) out[0] = red[0] * (1.0f / B_);
}

// ---------------------------------------------------------------------------
extern "C" void kernel_launch(void* const* d_in, const int* in_sizes, int n_in,
                              void* d_out, int out_size, void* d_ws, size_t ws_size,
                              hipStream_t stream) {
  const float* x = (const float*)d_in[0];
  const float* w = (const float*)d_in[1];
  const int* labels = (const int*)d_in[2];
  float* out = (float*)d_out;
  char* ws = (char*)d_ws;
  // ws layout (16B-aligned):
  //   xb : 1024*512 bf16 = 1,048,576 B
  //   S  : 1024 f32, Lb : 1024 f32
  unsigned short* xb = (unsigned short*)ws;
  float* S  = (float*)(ws + 1048576ull);
  float* Lb = (float*)(ws + 1052672ull);

  x_prep<<<256, 256, 0, stream>>>(x, xb, S);
  gemm_fused<<<6272, 256, 0, stream>>>(xb, w, labels, S, Lb);
  finalk<<<1, 256, 0, stream>>>(S, Lb, out);
}